// Round 2
// baseline (923.367 us; speedup 1.0000x reference)
//
#include <hip/hip_runtime.h>

#define N_NODES 100000
#define N_EDGES 1600000

// ---------------- CSR build ----------------

__global__ __launch_bounds__(256) void edge_pass1(const int* __restrict__ ei,
                                                  const float* __restrict__ ew,
                                                  float* __restrict__ deg,
                                                  int* __restrict__ cnt) {
    int e = blockIdx.x * 256 + threadIdx.x;
    if (e >= N_EDGES) return;
    int col = ei[N_EDGES + e];
    atomicAdd(&deg[col], ew[e]);
    atomicAdd(&cnt[col], 1);
}

__global__ __launch_bounds__(256) void node_pass(const float* __restrict__ deg,
                                                 const int* __restrict__ cnt,
                                                 float* __restrict__ dis,
                                                 int* __restrict__ offs,
                                                 int* __restrict__ gcur) {
    int j = blockIdx.x * 256 + threadIdx.x;
    int lane = threadIdx.x & 63;
    int c = 0;
    if (j < N_NODES) {
        dis[j] = rsqrtf(deg[j] + 1.0f);
        c = cnt[j];
    }
    // wave-level inclusive scan of counts -> one atomic per wave
    int s = c;
    #pragma unroll
    for (int off = 1; off < 64; off <<= 1) {
        int t = __shfl_up(s, off, 64);
        if (lane >= off) s += t;
    }
    int total = __shfl(s, 63, 64);
    int base = 0;
    if (lane == 0) base = atomicAdd(gcur, total);
    base = __shfl(base, 0, 64);
    if (j < N_NODES) offs[j] = base + (s - c);
}

__global__ __launch_bounds__(256) void edge_pass2(const int* __restrict__ ei,
                                                  const float* __restrict__ ew,
                                                  const float* __restrict__ dis,
                                                  const int* __restrict__ offs,
                                                  int* __restrict__ cursor,
                                                  int* __restrict__ csr_src,
                                                  float* __restrict__ csr_w) {
    int e = blockIdx.x * 256 + threadIdx.x;
    if (e >= N_EDGES) return;
    int row = ei[e];
    int col = ei[N_EDGES + e];
    int slot = offs[col] + atomicAdd(&cursor[col], 1);
    csr_src[slot] = row;
    csr_w[slot] = dis[row] * ew[e] * dis[col];
}

// ---------------- encoder layer 1: [N,16]@[16,128]+b, relu ----------------

__global__ __launch_bounds__(256) void enc1_kernel(const float* __restrict__ x,
                                                   const float* __restrict__ W1,
                                                   const float* __restrict__ b1,
                                                   float* __restrict__ out) {
    __shared__ float sW[16 * 128];
    __shared__ float sb[128];
    __shared__ float sx[2][16];
    int t = threadIdx.x;
    for (int i = t; i < 2048; i += 256) sW[i] = W1[i];
    if (t < 128) sb[t] = b1[t];
    __syncthreads();
    int half = t >> 7;   // row within pair
    int c = t & 127;     // output column
    for (int rp = blockIdx.x; rp < N_NODES / 2; rp += gridDim.x) {
        if (t < 32) {
            int r2 = t >> 4, k = t & 15;
            sx[r2][k] = x[(size_t)(rp * 2 + r2) * 16 + k];
        }
        __syncthreads();
        float acc = sb[c];
        #pragma unroll
        for (int k = 0; k < 16; k++) acc = fmaf(sx[half][k], sW[k * 128 + c], acc);
        out[(size_t)(rp * 2 + half) * 128 + c] = fmaxf(acc, 0.f);
        __syncthreads();
    }
}

// ---------------- [N,128]@[128,128] GEMM, optional bias/relu ----------------
// Block 256 threads; W fully resident in LDS (64KB); 32-row A tile (16KB).
// Thread (tx,ty): cols 4*tx..+3, rows ty*4..+3 -> 4x4 register tile.

__device__ __forceinline__ void fma4(float4& acc, float a, const float4& wv) {
    acc.x = fmaf(a, wv.x, acc.x);
    acc.y = fmaf(a, wv.y, acc.y);
    acc.z = fmaf(a, wv.z, acc.z);
    acc.w = fmaf(a, wv.w, acc.w);
}

template <bool BIAS, bool RELU>
__global__ __launch_bounds__(256) void gemm128(const float* __restrict__ A,
                                               const float* __restrict__ W,
                                               const float* __restrict__ bias,
                                               float* __restrict__ C) {
    __shared__ float sW[128 * 128];
    __shared__ float sA[32 * 128];
    int t = threadIdx.x;
    {
        const float4* Wv = (const float4*)W;
        float4* sWv = (float4*)sW;
        #pragma unroll
        for (int i = 0; i < 16; i++) sWv[t + i * 256] = Wv[t + i * 256];
    }
    int tx = t & 31;
    int ty = t >> 5;
    float4 bvec = make_float4(0.f, 0.f, 0.f, 0.f);
    if constexpr (BIAS) bvec = ((const float4*)bias)[tx];
    __syncthreads();

    for (int tile = blockIdx.x; tile < N_NODES / 32; tile += gridDim.x) {
        {
            const float4* Av = (const float4*)(A + (size_t)tile * 4096);
            float4* sAv = (float4*)sA;
            #pragma unroll
            for (int i = 0; i < 4; i++) sAv[t + i * 256] = Av[t + i * 256];
        }
        __syncthreads();

        float4 acc[4];
        #pragma unroll
        for (int r = 0; r < 4; r++) acc[r] = make_float4(0.f, 0.f, 0.f, 0.f);

        #pragma unroll 4
        for (int kk = 0; kk < 128; kk += 4) {
            float4 a0 = *(const float4*)(sA + (ty * 4 + 0) * 128 + kk);
            float4 a1 = *(const float4*)(sA + (ty * 4 + 1) * 128 + kk);
            float4 a2 = *(const float4*)(sA + (ty * 4 + 2) * 128 + kk);
            float4 a3 = *(const float4*)(sA + (ty * 4 + 3) * 128 + kk);
            float4 w0 = *(const float4*)(sW + (kk + 0) * 128 + tx * 4);
            float4 w1 = *(const float4*)(sW + (kk + 1) * 128 + tx * 4);
            float4 w2 = *(const float4*)(sW + (kk + 2) * 128 + tx * 4);
            float4 w3 = *(const float4*)(sW + (kk + 3) * 128 + tx * 4);
            fma4(acc[0], a0.x, w0); fma4(acc[0], a0.y, w1); fma4(acc[0], a0.z, w2); fma4(acc[0], a0.w, w3);
            fma4(acc[1], a1.x, w0); fma4(acc[1], a1.y, w1); fma4(acc[1], a1.z, w2); fma4(acc[1], a1.w, w3);
            fma4(acc[2], a2.x, w0); fma4(acc[2], a2.y, w1); fma4(acc[2], a2.z, w2); fma4(acc[2], a2.w, w3);
            fma4(acc[3], a3.x, w0); fma4(acc[3], a3.y, w1); fma4(acc[3], a3.z, w2); fma4(acc[3], a3.w, w3);
        }
        __syncthreads();

        float4* Cv = (float4*)(C + (size_t)tile * 4096);
        #pragma unroll
        for (int r = 0; r < 4; r++) {
            float4 v = acc[r];
            if constexpr (BIAS) { v.x += bvec.x; v.y += bvec.y; v.z += bvec.z; v.w += bvec.w; }
            if constexpr (RELU) {
                v.x = fmaxf(v.x, 0.f); v.y = fmaxf(v.y, 0.f);
                v.z = fmaxf(v.z, 0.f); v.w = fmaxf(v.w, 0.f);
            }
            Cv[(ty * 4 + r) * 32 + tx] = v;
        }
    }
}

// ---------------- GCN aggregation: out[j] = relu(sum_e w_e*m[src_e] + m[j]/deg_j + b) ----------------
// One wave per node; lane owns a float2 channel pair -> 512B coalesced gather per edge.

__global__ __launch_bounds__(256) void agg_kernel(const float* __restrict__ m,
                                                  const int* __restrict__ offs,
                                                  const int* __restrict__ cnt,
                                                  const int* __restrict__ csr_src,
                                                  const float* __restrict__ csr_w,
                                                  const float* __restrict__ dis,
                                                  const float* __restrict__ bias,
                                                  float* __restrict__ out) {
    int wave = threadIdx.x >> 6;
    int lane = threadIdx.x & 63;
    int j = blockIdx.x * 4 + wave;
    int c = lane * 2;
    float d = dis[j];
    float2 mm = *(const float2*)(m + (size_t)j * 128 + c);
    float acc0 = d * d * mm.x;
    float acc1 = d * d * mm.y;
    int start = offs[j];
    int num = cnt[j];
    for (int e = 0; e < num; e++) {
        int r = csr_src[start + e];
        float w = csr_w[start + e];
        float2 v = *(const float2*)(m + (size_t)r * 128 + c);
        acc0 = fmaf(w, v.x, acc0);
        acc1 = fmaf(w, v.y, acc1);
    }
    float2 b = *(const float2*)(bias + c);
    float2 o;
    o.x = fmaxf(acc0 + b.x, 0.f);
    o.y = fmaxf(acc1 + b.y, 0.f);
    *(float2*)(out + (size_t)j * 128 + c) = o;
}

// ---------------- decoder layer 2 + softmax: [N,128]@[128,2]+b, softmax ----------------

__global__ __launch_bounds__(256) void dec2_softmax(const float* __restrict__ d1,
                                                    const float* __restrict__ W2,
                                                    const float* __restrict__ b2,
                                                    float* __restrict__ out) {
    __shared__ float red[4][2];
    int t = threadIdx.x;
    int half = t >> 7;
    int c = t & 127;
    int row = blockIdx.x * 2 + half;
    float v = d1[(size_t)row * 128 + c];
    float p0 = v * W2[2 * c];
    float p1 = v * W2[2 * c + 1];
    #pragma unroll
    for (int off = 32; off; off >>= 1) {
        p0 += __shfl_down(p0, off, 64);
        p1 += __shfl_down(p1, off, 64);
    }
    int wv = t >> 6, ln = t & 63;
    if (ln == 0) { red[wv][0] = p0; red[wv][1] = p1; }
    __syncthreads();
    if ((t & 127) == 0) {
        int w0 = half * 2;
        float z0 = red[w0][0] + red[w0 + 1][0] + b2[0];
        float z1 = red[w0][1] + red[w0 + 1][1] + b2[1];
        float mx = fmaxf(z0, z1);
        float e0 = expf(z0 - mx);
        float e1 = expf(z1 - mx);
        float s = 1.f / (e0 + e1);
        *(float2*)(out + (size_t)row * 2) = make_float2(e0 * s, e1 * s);
    }
}

// ---------------- launch ----------------

extern "C" void kernel_launch(void* const* d_in, const int* in_sizes, int n_in,
                              void* d_out, int out_size, void* d_ws, size_t ws_size,
                              hipStream_t stream) {
    const float* x      = (const float*)d_in[0];
    const int*   ei     = (const int*)d_in[1];
    const float* ew     = (const float*)d_in[2];
    const float* enc_W1 = (const float*)d_in[3];
    const float* enc_b1 = (const float*)d_in[4];
    const float* enc_W2 = (const float*)d_in[5];
    const float* enc_b2 = (const float*)d_in[6];
    const float* c1_W   = (const float*)d_in[7];
    const float* c1_b   = (const float*)d_in[8];
    const float* c2_W   = (const float*)d_in[9];
    const float* c2_b   = (const float*)d_in[10];
    const float* dec_W1 = (const float*)d_in[11];
    const float* dec_b1 = (const float*)d_in[12];
    const float* dec_W2 = (const float*)d_in[13];
    const float* dec_b2 = (const float*)d_in[14];
    float* out = (float*)d_out;

    char* ws = (char*)d_ws;
    float* B1     = (float*)(ws);                       // 51,200,000 B
    float* B2     = (float*)(ws + 51200000);            // 51,200,000 B
    float* deg    = (float*)(ws + 102400000);           // 400,000 B
    int*   cnt    = (int*)  (ws + 102800000);           // 400,000 B
    int*   cursor = (int*)  (ws + 103200000);           // 400,000 B
    int*   gcur   = (int*)  (ws + 103600000);           // 256 B
    float* dis    = (float*)(ws + 103600256);           // 400,000 B
    int*   offs   = (int*)  (ws + 104000256);           // 400,000 B
    int*   csr_src= (int*)  (ws + 104400256);           // 6,400,000 B
    float* csr_w  = (float*)(ws + 110800256);           // 6,400,000 B
    // total 117,200,256 B

    // zero deg, cnt, cursor, gcur (contiguous)
    hipMemsetAsync(deg, 0, 1200256, stream);

    edge_pass1<<<(N_EDGES + 255) / 256, 256, 0, stream>>>(ei, ew, deg, cnt);
    node_pass<<<(N_NODES + 255) / 256, 256, 0, stream>>>(deg, cnt, dis, offs, gcur);
    edge_pass2<<<(N_EDGES + 255) / 256, 256, 0, stream>>>(ei, ew, dis, offs, cursor, csr_src, csr_w);

    enc1_kernel<<<2048, 256, 0, stream>>>(x, enc_W1, enc_b1, B2);
    gemm128<true, false><<<1024, 256, 0, stream>>>(B2, enc_W2, enc_b2, B1);

    gemm128<false, false><<<1024, 256, 0, stream>>>(B1, c1_W, nullptr, B2);
    agg_kernel<<<N_NODES / 4, 256, 0, stream>>>(B2, offs, cnt, csr_src, csr_w, dis, c1_b, B1);

    gemm128<false, false><<<1024, 256, 0, stream>>>(B1, c2_W, nullptr, B2);
    agg_kernel<<<N_NODES / 4, 256, 0, stream>>>(B2, offs, cnt, csr_src, csr_w, dis, c2_b, B1);

    gemm128<true, true><<<1024, 256, 0, stream>>>(B1, dec_W1, dec_b1, B2);
    dec2_softmax<<<N_NODES / 2, 256, 0, stream>>>(B2, dec_W2, dec_b2, out);
}

// Round 3
// 672.917 us; speedup vs baseline: 1.3722x; 1.3722x over previous
//
#include <hip/hip_runtime.h>

#define N_NODES 100000
#define N_EDGES 1600000

typedef _Float16 half8 __attribute__((ext_vector_type(8)));
typedef _Float16 half2v __attribute__((ext_vector_type(2)));
typedef float floatx4 __attribute__((ext_vector_type(4)));

// ---------------- CSR build ----------------

__global__ __launch_bounds__(256) void edge_pass1(const int* __restrict__ ei,
                                                  const float* __restrict__ ew,
                                                  float* __restrict__ deg,
                                                  int* __restrict__ cnt) {
    int e = blockIdx.x * 256 + threadIdx.x;
    if (e >= N_EDGES) return;
    int col = ei[N_EDGES + e];
    atomicAdd(&deg[col], ew[e]);
    atomicAdd(&cnt[col], 1);
}

__global__ __launch_bounds__(256) void node_pass(const float* __restrict__ deg,
                                                 const int* __restrict__ cnt,
                                                 float* __restrict__ dis,
                                                 int* __restrict__ offs,
                                                 int* __restrict__ gcur) {
    int j = blockIdx.x * 256 + threadIdx.x;
    int lane = threadIdx.x & 63;
    int c = 0;
    if (j < N_NODES) {
        dis[j] = rsqrtf(deg[j] + 1.0f);
        c = cnt[j];
    }
    int s = c;
    #pragma unroll
    for (int off = 1; off < 64; off <<= 1) {
        int t = __shfl_up(s, off, 64);
        if (lane >= off) s += t;
    }
    int total = __shfl(s, 63, 64);
    int base = 0;
    if (lane == 0) base = atomicAdd(gcur, total);
    base = __shfl(base, 0, 64);
    if (j < N_NODES) offs[j] = base + (s - c);
}

__global__ __launch_bounds__(256) void edge_pass2(const int* __restrict__ ei,
                                                  const float* __restrict__ ew,
                                                  const float* __restrict__ dis,
                                                  const int* __restrict__ offs,
                                                  int* __restrict__ cursor,
                                                  int* __restrict__ csr_src,
                                                  float* __restrict__ csr_w) {
    int e = blockIdx.x * 256 + threadIdx.x;
    if (e >= N_EDGES) return;
    int row = ei[e];
    int col = ei[N_EDGES + e];
    int slot = offs[col] + atomicAdd(&cursor[col], 1);
    csr_src[slot] = row;
    csr_w[slot] = dis[row] * ew[e] * dis[col];
}

// ---------------- weight prep: Wt[col][k] = (f16)W[k][col], 4 matrices ----------------

__global__ __launch_bounds__(256) void prep_w(const float* __restrict__ W0,
                                              const float* __restrict__ W1,
                                              const float* __restrict__ W2,
                                              const float* __restrict__ W3,
                                              _Float16* __restrict__ Wt) {
    int m = blockIdx.x >> 4;
    const float* W = (m == 0) ? W0 : (m == 1) ? W1 : (m == 2) ? W2 : W3;
    _Float16* o = Wt + m * 16384;
    int base = (blockIdx.x & 15) * 1024 + threadIdx.x * 4;
    int col = base >> 7;
    int k0 = base & 127;
    #pragma unroll
    for (int i = 0; i < 4; i++) o[base + i] = (_Float16)W[(k0 + i) * 128 + col];
}

// ---------------- encoder layer 1: [N,16]@[16,128]+b, relu -> f16 ----------------

__global__ __launch_bounds__(256) void enc1_kernel(const float* __restrict__ x,
                                                   const float* __restrict__ W1,
                                                   const float* __restrict__ b1,
                                                   _Float16* __restrict__ out) {
    __shared__ float sW[16 * 128];
    __shared__ float sb[128];
    __shared__ float sx[2][16];
    int t = threadIdx.x;
    for (int i = t; i < 2048; i += 256) sW[i] = W1[i];
    if (t < 128) sb[t] = b1[t];
    __syncthreads();
    int half = t >> 7;
    int c = t & 127;
    for (int rp = blockIdx.x; rp < N_NODES / 2; rp += gridDim.x) {
        if (t < 32) {
            int r2 = t >> 4, k = t & 15;
            sx[r2][k] = x[(size_t)(rp * 2 + r2) * 16 + k];
        }
        __syncthreads();
        float acc = sb[c];
        #pragma unroll
        for (int k = 0; k < 16; k++) acc = fmaf(sx[half][k], sW[k * 128 + c], acc);
        out[(size_t)(rp * 2 + half) * 128 + c] = (_Float16)fmaxf(acc, 0.f);
        __syncthreads();
    }
}

// ---------------- f16 MFMA GEMM: [N,128] @ [128,128] -> f16, optional bias/relu ----------------
// Block = 256 thr = 4 waves; one 64-row tile per block.
// B (=W) fragments hoisted to registers (128 VGPR), reused; A staged via
// global_load_lds w/ XOR-swizzled source; LDS-transpose epilogue.

template <bool BIAS, bool RELU>
__global__ __launch_bounds__(256, 2) void gemm_mfma(const _Float16* __restrict__ A,
                                                    const _Float16* __restrict__ Wt,
                                                    const float* __restrict__ bias,
                                                    _Float16* __restrict__ C) {
    __shared__ _Float16 sA[64 * 128];   // 16 KB (swizzled 16B chunks)
    __shared__ _Float16 sE[64 * 128];   // 16 KB epilogue
    int t = threadIdx.x;
    int lane = t & 63;
    int w = t >> 6;
    int l15 = lane & 15;
    int l4 = lane >> 4;

    // B fragments: bfrag[n][kk] -> lane supplies B[k = kk*32 + l4*8 + j][col = n*16 + l15]
    half8 bfrag[8][4];
    #pragma unroll
    for (int n = 0; n < 8; n++)
        #pragma unroll
        for (int kk = 0; kk < 4; kk++)
            bfrag[n][kk] = *(const half8*)(Wt + (n * 16 + l15) * 128 + kk * 32 + l4 * 8);

    float bcol[8];
    if constexpr (BIAS) {
        #pragma unroll
        for (int n = 0; n < 8; n++) bcol[n] = bias[n * 16 + l15];
    }

    int tile = blockIdx.x;
    const _Float16* Ag = A + (size_t)tile * 64 * 128;

    // stage 64 rows x 256 B; chunk c = i*256 + t; LDS linear, source pre-swizzled
    #pragma unroll
    for (int i = 0; i < 4; i++) {
        int c = i * 256 + t;
        int row = c >> 4;
        int g = (c & 15) ^ (row & 7);
        const _Float16* src = Ag + row * 128 + g * 8;
        __builtin_amdgcn_global_load_lds(
            (const __attribute__((address_space(1))) void*)src,
            (__attribute__((address_space(3))) void*)(sA + (size_t)(i * 256 + w * 64) * 8),
            16, 0, 0);
    }
    __syncthreads();

    floatx4 acc[8];
    #pragma unroll
    for (int n = 0; n < 8; n++) acc[n] = (floatx4)(0.f);

    #pragma unroll
    for (int kk = 0; kk < 4; kk++) {
        int rloc = w * 16 + l15;
        int cl = kk * 4 + l4;
        int s = cl ^ (rloc & 7);
        half8 af = *(const half8*)(sA + rloc * 128 + s * 8);
        #pragma unroll
        for (int n = 0; n < 8; n++)
            acc[n] = __builtin_amdgcn_mfma_f32_16x16x32_f16(af, bfrag[n][kk], acc[n], 0, 0, 0);
    }

    // epilogue: D[row=(l>>4)*4+r][col=l15] per col-block n
    #pragma unroll
    for (int n = 0; n < 8; n++) {
        #pragma unroll
        for (int r = 0; r < 4; r++) {
            float v = acc[n][r];
            if constexpr (BIAS) v += bcol[n];
            if constexpr (RELU) v = fmaxf(v, 0.f);
            int row = w * 16 + l4 * 4 + r;
            sE[row * 128 + n * 16 + l15] = (_Float16)v;
        }
    }
    __syncthreads();

    size_t base_row = (size_t)tile * 64;
    #pragma unroll
    for (int i = 0; i < 4; i++) {
        int c = i * 256 + t;
        int row = c >> 4;
        if (base_row + row < N_NODES) {
            *(float4*)((char*)C + (base_row + row) * 256 + (c & 15) * 16) =
                *(const float4*)((const char*)sE + (size_t)c * 16);
        }
    }
}

// ---------------- GCN aggregation (f16 rows, fp32 accum), 4-way unrolled ----------------

__global__ __launch_bounds__(256) void agg_kernel(const _Float16* __restrict__ m,
                                                  const int* __restrict__ offs,
                                                  const int* __restrict__ cnt,
                                                  const int* __restrict__ csr_src,
                                                  const float* __restrict__ csr_w,
                                                  const float* __restrict__ dis,
                                                  const float* __restrict__ bias,
                                                  _Float16* __restrict__ out) {
    int wave = threadIdx.x >> 6;
    int lane = threadIdx.x & 63;
    int j = blockIdx.x * 4 + wave;
    int c = lane * 2;
    float d = dis[j];
    float dd = d * d;
    half2v mm = *(const half2v*)(m + (size_t)j * 128 + c);
    float a0x = dd * (float)mm[0], a0y = dd * (float)mm[1];
    float a1x = 0.f, a1y = 0.f, a2x = 0.f, a2y = 0.f, a3x = 0.f, a3y = 0.f;
    int s = offs[j];
    int num = cnt[j];
    int e = 0;
    for (; e + 4 <= num; e += 4) {
        int r0 = csr_src[s + e + 0]; float w0 = csr_w[s + e + 0];
        int r1 = csr_src[s + e + 1]; float w1 = csr_w[s + e + 1];
        int r2 = csr_src[s + e + 2]; float w2 = csr_w[s + e + 2];
        int r3 = csr_src[s + e + 3]; float w3 = csr_w[s + e + 3];
        half2v v0 = *(const half2v*)(m + (size_t)r0 * 128 + c);
        half2v v1 = *(const half2v*)(m + (size_t)r1 * 128 + c);
        half2v v2 = *(const half2v*)(m + (size_t)r2 * 128 + c);
        half2v v3 = *(const half2v*)(m + (size_t)r3 * 128 + c);
        a0x = fmaf(w0, (float)v0[0], a0x); a0y = fmaf(w0, (float)v0[1], a0y);
        a1x = fmaf(w1, (float)v1[0], a1x); a1y = fmaf(w1, (float)v1[1], a1y);
        a2x = fmaf(w2, (float)v2[0], a2x); a2y = fmaf(w2, (float)v2[1], a2y);
        a3x = fmaf(w3, (float)v3[0], a3x); a3y = fmaf(w3, (float)v3[1], a3y);
    }
    for (; e < num; e++) {
        int r0 = csr_src[s + e]; float w0 = csr_w[s + e];
        half2v v0 = *(const half2v*)(m + (size_t)r0 * 128 + c);
        a0x = fmaf(w0, (float)v0[0], a0x); a0y = fmaf(w0, (float)v0[1], a0y);
    }
    float rx = (a0x + a1x) + (a2x + a3x) + bias[c];
    float ry = (a0y + a1y) + (a2y + a3y) + bias[c + 1];
    half2v o;
    o[0] = (_Float16)fmaxf(rx, 0.f);
    o[1] = (_Float16)fmaxf(ry, 0.f);
    *(half2v*)(out + (size_t)j * 128 + c) = o;
}

// ---------------- decoder layer 2 + softmax: f16 [N,128]@[128,2]+b, softmax -> fp32 ----------------

__global__ __launch_bounds__(256) void dec2_softmax(const _Float16* __restrict__ d1,
                                                    const float* __restrict__ W2,
                                                    const float* __restrict__ b2,
                                                    float* __restrict__ out) {
    __shared__ float red[4][2];
    int t = threadIdx.x;
    int half = t >> 7;
    int c = t & 127;
    int row = blockIdx.x * 2 + half;
    float v = (float)d1[(size_t)row * 128 + c];
    float p0 = v * W2[2 * c];
    float p1 = v * W2[2 * c + 1];
    #pragma unroll
    for (int off = 32; off; off >>= 1) {
        p0 += __shfl_down(p0, off, 64);
        p1 += __shfl_down(p1, off, 64);
    }
    int wv = t >> 6, ln = t & 63;
    if (ln == 0) { red[wv][0] = p0; red[wv][1] = p1; }
    __syncthreads();
    if ((t & 127) == 0) {
        int w0 = half * 2;
        float z0 = red[w0][0] + red[w0 + 1][0] + b2[0];
        float z1 = red[w0][1] + red[w0 + 1][1] + b2[1];
        float mx = fmaxf(z0, z1);
        float e0 = expf(z0 - mx);
        float e1 = expf(z1 - mx);
        float s = 1.f / (e0 + e1);
        *(float2*)(out + (size_t)row * 2) = make_float2(e0 * s, e1 * s);
    }
}

// ---------------- launch ----------------

extern "C" void kernel_launch(void* const* d_in, const int* in_sizes, int n_in,
                              void* d_out, int out_size, void* d_ws, size_t ws_size,
                              hipStream_t stream) {
    const float* x      = (const float*)d_in[0];
    const int*   ei     = (const int*)d_in[1];
    const float* ew     = (const float*)d_in[2];
    const float* enc_W1 = (const float*)d_in[3];
    const float* enc_b1 = (const float*)d_in[4];
    const float* enc_W2 = (const float*)d_in[5];
    const float* enc_b2 = (const float*)d_in[6];
    const float* c1_W   = (const float*)d_in[7];
    const float* c1_b   = (const float*)d_in[8];
    const float* c2_W   = (const float*)d_in[9];
    const float* c2_b   = (const float*)d_in[10];
    const float* dec_W1 = (const float*)d_in[11];
    const float* dec_b1 = (const float*)d_in[12];
    const float* dec_W2 = (const float*)d_in[13];
    const float* dec_b2 = (const float*)d_in[14];
    float* out = (float*)d_out;

    char* ws = (char*)d_ws;
    _Float16* B1     = (_Float16*)(ws);                 // 25,600,000 B
    _Float16* B2     = (_Float16*)(ws + 25600000);      // 25,600,000 B
    _Float16* Wt     = (_Float16*)(ws + 51200000);      // 131,072 B (4 x 128x128 f16)
    float* deg    = (float*)(ws + 51331072);            // 400,000 B
    int*   cnt    = (int*)  (ws + 51731072);            // 400,000 B
    int*   cursor = (int*)  (ws + 52131072);            // 400,000 B
    int*   gcur   = (int*)  (ws + 52531072);            // 256 B
    float* dis    = (float*)(ws + 52531328);            // 400,000 B
    int*   offs   = (int*)  (ws + 52931328);            // 400,000 B
    int*   csr_src= (int*)  (ws + 53331328);            // 6,400,000 B
    float* csr_w  = (float*)(ws + 59731328);            // 6,400,000 B
    // end ~66.1 MB

    // zero deg, cnt, cursor, gcur (contiguous)
    hipMemsetAsync(deg, 0, 1200256, stream);

    edge_pass1<<<(N_EDGES + 255) / 256, 256, 0, stream>>>(ei, ew, deg, cnt);
    node_pass<<<(N_NODES + 255) / 256, 256, 0, stream>>>(deg, cnt, dis, offs, gcur);
    edge_pass2<<<(N_EDGES + 255) / 256, 256, 0, stream>>>(ei, ew, dis, offs, cursor, csr_src, csr_w);

    prep_w<<<64, 256, 0, stream>>>(enc_W2, c1_W, c2_W, dec_W1, Wt);
    enc1_kernel<<<2048, 256, 0, stream>>>(x, enc_W1, enc_b1, B1);

    const int NT = (N_NODES + 63) / 64;  // 1563 tiles
    // enc layer 2: B1 @ enc_W2 + b2 -> B2
    gemm_mfma<true, false><<<NT, 256, 0, stream>>>(B1, Wt + 0 * 16384, enc_b2, B2);
    // conv1 transform: B2 @ c1_W -> B1
    gemm_mfma<false, false><<<NT, 256, 0, stream>>>(B2, Wt + 1 * 16384, nullptr, B1);
    agg_kernel<<<N_NODES / 4, 256, 0, stream>>>(B1, offs, cnt, csr_src, csr_w, dis, c1_b, B2);
    // conv2 transform: B2 @ c2_W -> B1
    gemm_mfma<false, false><<<NT, 256, 0, stream>>>(B2, Wt + 2 * 16384, nullptr, B1);
    agg_kernel<<<N_NODES / 4, 256, 0, stream>>>(B1, offs, cnt, csr_src, csr_w, dis, c2_b, B2);
    // decoder layer 1: B2 @ dec_W1 + b, relu -> B1
    gemm_mfma<true, true><<<NT, 256, 0, stream>>>(B2, Wt + 3 * 16384, dec_b1, B1);
    dec2_softmax<<<N_NODES / 2, 256, 0, stream>>>(B1, dec_W2, dec_b2, out);
}

// Round 4
// 470.654 us; speedup vs baseline: 1.9619x; 1.4297x over previous
//
#include <hip/hip_runtime.h>

#define N_NODES 100000
#define N_EDGES 1600000

typedef _Float16 half8 __attribute__((ext_vector_type(8)));
typedef _Float16 half2v __attribute__((ext_vector_type(2)));
typedef float floatx4 __attribute__((ext_vector_type(4)));

// ---------------- CSR build ----------------
// pass1: single packed u64 atomic per edge: [count:24 | weight-sum fixed20:40]
// returned old value's count field = this edge's slot ticket within its node.

__global__ __launch_bounds__(256) void edge_pass1(const int* __restrict__ ei,
                                                  const float* __restrict__ ew,
                                                  unsigned long long* __restrict__ packed,
                                                  unsigned short* __restrict__ tickets) {
    int e = blockIdx.x * 256 + threadIdx.x;
    if (e >= N_EDGES) return;
    int col = ei[N_EDGES + e];
    unsigned fx = (unsigned)(ew[e] * 1048576.0f + 0.5f);
    unsigned long long old = atomicAdd(&packed[col], (1ULL << 40) | (unsigned long long)fx);
    tickets[e] = (unsigned short)(old >> 40);
}

__global__ __launch_bounds__(256) void node_pass(const unsigned long long* __restrict__ packed,
                                                 float* __restrict__ dis,
                                                 int* __restrict__ offs,
                                                 int* __restrict__ gcur) {
    int j = blockIdx.x * 256 + threadIdx.x;
    int lane = threadIdx.x & 63;
    int c = 0;
    if (j < N_NODES) {
        unsigned long long v = packed[j];
        c = (int)(v >> 40);
        float deg = (float)(v & ((1ULL << 40) - 1)) * (1.0f / 1048576.0f);
        dis[j] = rsqrtf(deg + 1.0f);
    }
    // wave-level inclusive scan of counts -> one atomic per wave
    int s = c;
    #pragma unroll
    for (int off = 1; off < 64; off <<= 1) {
        int t = __shfl_up(s, off, 64);
        if (lane >= off) s += t;
    }
    int total = __shfl(s, 63, 64);
    int base = 0;
    if (lane == 0) base = atomicAdd(gcur, total);
    base = __shfl(base, 0, 64);
    if (j < N_NODES) offs[j] = base + (s - c);
}

__global__ __launch_bounds__(256) void edge_pass2(const int* __restrict__ ei,
                                                  const float* __restrict__ ew,
                                                  const float* __restrict__ dis,
                                                  const int* __restrict__ offs,
                                                  const unsigned short* __restrict__ tickets,
                                                  int2* __restrict__ csr) {
    int e = blockIdx.x * 256 + threadIdx.x;
    if (e >= N_EDGES) return;
    int row = ei[e];
    int col = ei[N_EDGES + e];
    int slot = offs[col] + (int)tickets[e];
    float nw = dis[row] * ew[e] * dis[col];
    csr[slot] = make_int2(row, __float_as_int(nw));
}

// ---------------- weight prep: Wt[col][k] = (f16)W[k][col], 4 matrices ----------------

__global__ __launch_bounds__(256) void prep_w(const float* __restrict__ W0,
                                              const float* __restrict__ W1,
                                              const float* __restrict__ W2,
                                              const float* __restrict__ W3,
                                              _Float16* __restrict__ Wt) {
    int m = blockIdx.x >> 4;
    const float* W = (m == 0) ? W0 : (m == 1) ? W1 : (m == 2) ? W2 : W3;
    _Float16* o = Wt + m * 16384;
    int base = (blockIdx.x & 15) * 1024 + threadIdx.x * 4;
    int col = base >> 7;
    int k0 = base & 127;
    #pragma unroll
    for (int i = 0; i < 4; i++) o[base + i] = (_Float16)W[(k0 + i) * 128 + col];
}

// ---------------- encoder layer 1: [N,16]@[16,128]+b, relu -> f16 ----------------
// 256 rows per block; x tile in padded LDS (stride 17 words -> conflict-free).

__global__ __launch_bounds__(256) void enc1_kernel(const float* __restrict__ x,
                                                   const float* __restrict__ W1,
                                                   const float* __restrict__ b1,
                                                   _Float16* __restrict__ out) {
    __shared__ float sX[256 * 17];
    __shared__ float sW[2048];
    __shared__ float sb[128];
    int t = threadIdx.x;
    int base = blockIdx.x * 256;
    for (int i = t; i < 512; i += 256) ((float4*)sW)[i] = ((const float4*)W1)[i];
    if (t < 128) sb[t] = b1[t];
    #pragma unroll
    for (int i = 0; i < 4; i++) {
        int f = i * 1024 + t * 4;
        int row = f >> 4, k = f & 15;
        float4 v = make_float4(0.f, 0.f, 0.f, 0.f);
        if (base + row < N_NODES) v = *(const float4*)(x + (size_t)(base + row) * 16 + k);
        *(float4*)(sX + row * 17 + k) = v;
    }
    __syncthreads();
    int row = base + t;
    if (row >= N_NODES) return;
    float xr[16];
    #pragma unroll
    for (int k = 0; k < 16; k++) xr[k] = sX[t * 17 + k];
    #pragma unroll 4
    for (int cb = 0; cb < 16; cb++) {
        float acc[8];
        #pragma unroll
        for (int jj = 0; jj < 8; jj++) acc[jj] = sb[cb * 8 + jj];
        #pragma unroll
        for (int k = 0; k < 16; k++) {
            float xv = xr[k];
            #pragma unroll
            for (int jj = 0; jj < 8; jj++) acc[jj] = fmaf(xv, sW[k * 128 + cb * 8 + jj], acc[jj]);
        }
        half8 h;
        #pragma unroll
        for (int jj = 0; jj < 8; jj++) h[jj] = (_Float16)fmaxf(acc[jj], 0.f);
        *(half8*)(out + (size_t)row * 128 + cb * 8) = h;
    }
}

// ---------------- f16 MFMA GEMM: [N,128] @ [128,128], grid-stride tiles ----------------
// W fragments hoisted to 128 VGPRs; A staged via global_load_lds (swizzled source).
// DEC variant fuses decoder layer2 + softmax straight from the accumulators.

#define GEMM_GRID 522

template <bool BIAS, bool RELU, bool DEC>
__global__ __launch_bounds__(256, 2) void gemm_mfma(const _Float16* __restrict__ A,
                                                    const _Float16* __restrict__ Wt,
                                                    const float* __restrict__ bias,
                                                    _Float16* __restrict__ C,
                                                    const float* __restrict__ W2,
                                                    const float* __restrict__ b2,
                                                    float* __restrict__ sm_out) {
    __shared__ _Float16 sA[64 * 128];
    __shared__ _Float16 sE[DEC ? 64 : 64 * 128];
    __shared__ float sW2[DEC ? 256 : 1];
    int t = threadIdx.x;
    int lane = t & 63;
    int w = t >> 6;
    int l15 = lane & 15;
    int l4 = lane >> 4;

    // B fragments: bfrag[n][kk] -> lane supplies B[k = kk*32 + l4*8 + j][col = n*16 + l15]
    half8 bfrag[8][4];
    #pragma unroll
    for (int n = 0; n < 8; n++)
        #pragma unroll
        for (int kk = 0; kk < 4; kk++)
            bfrag[n][kk] = *(const half8*)(Wt + (n * 16 + l15) * 128 + kk * 32 + l4 * 8);

    float bcol[8];
    if constexpr (BIAS) {
        #pragma unroll
        for (int n = 0; n < 8; n++) bcol[n] = bias[n * 16 + l15];
    }
    float b20 = 0.f, b21 = 0.f;
    if constexpr (DEC) {
        if (t < 256) sW2[t] = W2[t];
        b20 = b2[0]; b21 = b2[1];
    }

    const int NT = (N_NODES + 63) / 64;
    for (int tile = blockIdx.x; tile < NT; tile += GEMM_GRID) {
        const _Float16* Ag = A + (size_t)tile * 64 * 128;
        #pragma unroll
        for (int i = 0; i < 4; i++) {
            int c = i * 256 + t;
            int row = c >> 4;
            int g = (c & 15) ^ (row & 7);
            const _Float16* src = Ag + row * 128 + g * 8;
            __builtin_amdgcn_global_load_lds(
                (const __attribute__((address_space(1))) void*)src,
                (__attribute__((address_space(3))) void*)(sA + (size_t)(i * 256 + w * 64) * 8),
                16, 0, 0);
        }
        __syncthreads();

        floatx4 acc[8];
        #pragma unroll
        for (int n = 0; n < 8; n++) acc[n] = (floatx4)(0.f);

        #pragma unroll
        for (int kk = 0; kk < 4; kk++) {
            int rloc = w * 16 + l15;
            int cl = kk * 4 + l4;
            int s = cl ^ (rloc & 7);
            half8 af = *(const half8*)(sA + rloc * 128 + s * 8);
            #pragma unroll
            for (int n = 0; n < 8; n++)
                acc[n] = __builtin_amdgcn_mfma_f32_16x16x32_f16(af, bfrag[n][kk], acc[n], 0, 0, 0);
        }

        size_t base_row = (size_t)tile * 64;
        if constexpr (DEC) {
            // project each row onto W2 (2 cols) + softmax, straight from accumulators.
            // lane (l4,l15) holds D[w*16+l4*4+r][n*16+l15], n=0..8.
            #pragma unroll
            for (int r = 0; r < 4; r++) {
                float p0 = 0.f, p1 = 0.f;
                #pragma unroll
                for (int n = 0; n < 8; n++) {
                    float v = acc[n][r];
                    if constexpr (BIAS) v += bcol[n];
                    if constexpr (RELU) v = fmaxf(v, 0.f);
                    int ch = n * 16 + l15;
                    p0 = fmaf(v, sW2[ch * 2 + 0], p0);
                    p1 = fmaf(v, sW2[ch * 2 + 1], p1);
                }
                #pragma unroll
                for (int m = 1; m < 16; m <<= 1) {
                    p0 += __shfl_xor(p0, m, 64);
                    p1 += __shfl_xor(p1, m, 64);
                }
                size_t grow = base_row + w * 16 + l4 * 4 + r;
                if (l15 == 0 && grow < N_NODES) {
                    float z0 = p0 + b20, z1 = p1 + b21;
                    float mx = fmaxf(z0, z1);
                    float e0 = expf(z0 - mx), e1 = expf(z1 - mx);
                    float si = 1.f / (e0 + e1);
                    *(float2*)(sm_out + grow * 2) = make_float2(e0 * si, e1 * si);
                }
            }
            __syncthreads();   // protect sA before next tile's staging
        } else {
            #pragma unroll
            for (int n = 0; n < 8; n++) {
                #pragma unroll
                for (int r = 0; r < 4; r++) {
                    float v = acc[n][r];
                    if constexpr (BIAS) v += bcol[n];
                    if constexpr (RELU) v = fmaxf(v, 0.f);
                    int row = w * 16 + l4 * 4 + r;
                    sE[row * 128 + n * 16 + l15] = (_Float16)v;
                }
            }
            __syncthreads();
            #pragma unroll
            for (int i = 0; i < 4; i++) {
                int c = i * 256 + t;
                int row = c >> 4;
                if (base_row + row < N_NODES) {
                    *(float4*)((char*)C + (base_row + row) * 256 + (c & 15) * 16) =
                        *(const float4*)((const char*)sE + (size_t)c * 16);
                }
            }
        }
    }
}

// ---------------- GCN aggregation (f16 rows, fp32 accum), 4-way unrolled ----------------

__global__ __launch_bounds__(256) void agg_kernel(const _Float16* __restrict__ m,
                                                  const int* __restrict__ offs,
                                                  const unsigned long long* __restrict__ packed,
                                                  const int2* __restrict__ csr,
                                                  const float* __restrict__ dis,
                                                  const float* __restrict__ bias,
                                                  _Float16* __restrict__ out) {
    int wave = threadIdx.x >> 6;
    int lane = threadIdx.x & 63;
    int j = blockIdx.x * 4 + wave;
    int c = lane * 2;
    float d = dis[j];
    float dd = d * d;
    half2v mm = *(const half2v*)(m + (size_t)j * 128 + c);
    float a0x = dd * (float)mm[0], a0y = dd * (float)mm[1];
    float a1x = 0.f, a1y = 0.f, a2x = 0.f, a2y = 0.f, a3x = 0.f, a3y = 0.f;
    int s = offs[j];
    int num = (int)(packed[j] >> 40);
    int e = 0;
    for (; e + 4 <= num; e += 4) {
        int2 p0 = csr[s + e + 0];
        int2 p1 = csr[s + e + 1];
        int2 p2 = csr[s + e + 2];
        int2 p3 = csr[s + e + 3];
        half2v v0 = *(const half2v*)(m + (size_t)p0.x * 128 + c);
        half2v v1 = *(const half2v*)(m + (size_t)p1.x * 128 + c);
        half2v v2 = *(const half2v*)(m + (size_t)p2.x * 128 + c);
        half2v v3 = *(const half2v*)(m + (size_t)p3.x * 128 + c);
        float w0 = __int_as_float(p0.y), w1 = __int_as_float(p1.y);
        float w2 = __int_as_float(p2.y), w3 = __int_as_float(p3.y);
        a0x = fmaf(w0, (float)v0[0], a0x); a0y = fmaf(w0, (float)v0[1], a0y);
        a1x = fmaf(w1, (float)v1[0], a1x); a1y = fmaf(w1, (float)v1[1], a1y);
        a2x = fmaf(w2, (float)v2[0], a2x); a2y = fmaf(w2, (float)v2[1], a2y);
        a3x = fmaf(w3, (float)v3[0], a3x); a3y = fmaf(w3, (float)v3[1], a3y);
    }
    for (; e < num; e++) {
        int2 p0 = csr[s + e];
        float w0 = __int_as_float(p0.y);
        half2v v0 = *(const half2v*)(m + (size_t)p0.x * 128 + c);
        a0x = fmaf(w0, (float)v0[0], a0x); a0y = fmaf(w0, (float)v0[1], a0y);
    }
    float rx = (a0x + a1x) + (a2x + a3x) + bias[c];
    float ry = (a0y + a1y) + (a2y + a3y) + bias[c + 1];
    half2v o;
    o[0] = (_Float16)fmaxf(rx, 0.f);
    o[1] = (_Float16)fmaxf(ry, 0.f);
    *(half2v*)(out + (size_t)j * 128 + c) = o;
}

// ---------------- launch ----------------

extern "C" void kernel_launch(void* const* d_in, const int* in_sizes, int n_in,
                              void* d_out, int out_size, void* d_ws, size_t ws_size,
                              hipStream_t stream) {
    const float* x      = (const float*)d_in[0];
    const int*   ei     = (const int*)d_in[1];
    const float* ew     = (const float*)d_in[2];
    const float* enc_W1 = (const float*)d_in[3];
    const float* enc_b1 = (const float*)d_in[4];
    const float* enc_W2 = (const float*)d_in[5];
    const float* enc_b2 = (const float*)d_in[6];
    const float* c1_W   = (const float*)d_in[7];
    const float* c1_b   = (const float*)d_in[8];
    const float* c2_W   = (const float*)d_in[9];
    const float* c2_b   = (const float*)d_in[10];
    const float* dec_W1 = (const float*)d_in[11];
    const float* dec_b1 = (const float*)d_in[12];
    const float* dec_W2 = (const float*)d_in[13];
    const float* dec_b2 = (const float*)d_in[14];
    float* out = (float*)d_out;

    char* ws = (char*)d_ws;
    _Float16* B1 = (_Float16*)(ws);                          // 25,600,000
    _Float16* B2 = (_Float16*)(ws + 25600000);               // 25,600,000
    _Float16* Wt = (_Float16*)(ws + 51200000);               // 131,072
    unsigned long long* packed = (unsigned long long*)(ws + 51331072);  // 800,000
    int*   gcur    = (int*)  (ws + 52131072);                // 256
    float* dis     = (float*)(ws + 52131328);                // 400,000
    int*   offs    = (int*)  (ws + 52531328);                // 400,000
    unsigned short* tickets = (unsigned short*)(ws + 52931328); // 3,200,000
    int2*  csr     = (int2*) (ws + 56131328);                // 12,800,000
    // end ~68.9 MB

    // zero packed + gcur (contiguous)
    hipMemsetAsync(packed, 0, 800256, stream);

    edge_pass1<<<(N_EDGES + 255) / 256, 256, 0, stream>>>(ei, ew, packed, tickets);
    node_pass<<<(N_NODES + 255) / 256, 256, 0, stream>>>(packed, dis, offs, gcur);
    edge_pass2<<<(N_EDGES + 255) / 256, 256, 0, stream>>>(ei, ew, dis, offs, tickets, csr);

    prep_w<<<64, 256, 0, stream>>>(enc_W2, c1_W, c2_W, dec_W1, Wt);
    enc1_kernel<<<(N_NODES + 255) / 256, 256, 0, stream>>>(x, enc_W1, enc_b1, B1);

    // enc layer 2
    gemm_mfma<true, false, false><<<GEMM_GRID, 256, 0, stream>>>(B1, Wt + 0 * 16384, enc_b2, B2, nullptr, nullptr, nullptr);
    // conv1 transform + aggregate
    gemm_mfma<false, false, false><<<GEMM_GRID, 256, 0, stream>>>(B2, Wt + 1 * 16384, nullptr, B1, nullptr, nullptr, nullptr);
    agg_kernel<<<N_NODES / 4, 256, 0, stream>>>(B1, offs, packed, csr, dis, c1_b, B2);
    // conv2 transform + aggregate
    gemm_mfma<false, false, false><<<GEMM_GRID, 256, 0, stream>>>(B2, Wt + 2 * 16384, nullptr, B1, nullptr, nullptr, nullptr);
    agg_kernel<<<N_NODES / 4, 256, 0, stream>>>(B1, offs, packed, csr, dis, c2_b, B2);
    // decoder layer 1 + layer 2 + softmax (fused)
    gemm_mfma<true, true, true><<<GEMM_GRID, 256, 0, stream>>>(B2, Wt + 3 * 16384, dec_b1, nullptr, dec_W2, dec_b2, out);
}

// Round 5
// 452.006 us; speedup vs baseline: 2.0428x; 1.0413x over previous
//
#include <hip/hip_runtime.h>

#define N_NODES 100000
#define N_EDGES 1600000

typedef _Float16 half8 __attribute__((ext_vector_type(8)));
typedef float floatx4 __attribute__((ext_vector_type(4)));

// ---------------- CSR build ----------------
// pass1: single packed u64 atomic per edge: [count:24 | weight-sum fixed20:40]
// returned old value's count field = this edge's slot ticket within its node.

__global__ __launch_bounds__(256) void edge_pass1(const int* __restrict__ ei,
                                                  const float* __restrict__ ew,
                                                  unsigned long long* __restrict__ packed,
                                                  unsigned short* __restrict__ tickets) {
    int e = blockIdx.x * 256 + threadIdx.x;
    if (e >= N_EDGES) return;
    int col = ei[N_EDGES + e];
    unsigned fx = (unsigned)(ew[e] * 1048576.0f + 0.5f);
    unsigned long long old = atomicAdd(&packed[col], (1ULL << 40) | (unsigned long long)fx);
    tickets[e] = (unsigned short)(old >> 40);
}

__global__ __launch_bounds__(256) void node_pass(const unsigned long long* __restrict__ packed,
                                                 float* __restrict__ dis,
                                                 int* __restrict__ offs,
                                                 int* __restrict__ gcur) {
    int j = blockIdx.x * 256 + threadIdx.x;
    int lane = threadIdx.x & 63;
    int c = 0;
    if (j < N_NODES) {
        unsigned long long v = packed[j];
        c = (int)(v >> 40);
        float deg = (float)(v & ((1ULL << 40) - 1)) * (1.0f / 1048576.0f);
        dis[j] = rsqrtf(deg + 1.0f);
    }
    // wave-level inclusive scan of counts -> one atomic per wave
    int s = c;
    #pragma unroll
    for (int off = 1; off < 64; off <<= 1) {
        int t = __shfl_up(s, off, 64);
        if (lane >= off) s += t;
    }
    int total = __shfl(s, 63, 64);
    int base = 0;
    if (lane == 0) base = atomicAdd(gcur, total);
    base = __shfl(base, 0, 64);
    if (j < N_NODES) offs[j] = base + (s - c);
}

// csr entry: [f16 weight bits sans sign :15 | src :17]
__global__ __launch_bounds__(256) void edge_pass2(const int* __restrict__ ei,
                                                  const float* __restrict__ ew,
                                                  const float* __restrict__ dis,
                                                  const int* __restrict__ offs,
                                                  const unsigned short* __restrict__ tickets,
                                                  unsigned* __restrict__ csr) {
    int e = blockIdx.x * 256 + threadIdx.x;
    if (e >= N_EDGES) return;
    int row = ei[e];
    int col = ei[N_EDGES + e];
    int slot = offs[col] + (int)tickets[e];
    float nw = dis[row] * ew[e] * dis[col];
    _Float16 h = (_Float16)nw;
    unsigned short hb;
    __builtin_memcpy(&hb, &h, 2);
    csr[slot] = ((unsigned)hb << 17) | (unsigned)row;
}

// ---------------- weight prep: Wt[col][k] = (f16)W[k][col], 4 matrices ----------------

__global__ __launch_bounds__(256) void prep_w(const float* __restrict__ W0,
                                              const float* __restrict__ W1,
                                              const float* __restrict__ W2,
                                              const float* __restrict__ W3,
                                              _Float16* __restrict__ Wt) {
    int m = blockIdx.x >> 4;
    const float* W = (m == 0) ? W0 : (m == 1) ? W1 : (m == 2) ? W2 : W3;
    _Float16* o = Wt + m * 16384;
    int base = (blockIdx.x & 15) * 1024 + threadIdx.x * 4;
    int col = base >> 7;
    int k0 = base & 127;
    #pragma unroll
    for (int i = 0; i < 4; i++) o[base + i] = (_Float16)W[(k0 + i) * 128 + col];
}

// ---------------- encoder layer 1: [N,16]@[16,128]+b, relu -> f16 ----------------

__global__ __launch_bounds__(256) void enc1_kernel(const float* __restrict__ x,
                                                   const float* __restrict__ W1,
                                                   const float* __restrict__ b1,
                                                   _Float16* __restrict__ out) {
    __shared__ float sX[256 * 17];
    __shared__ float sW[2048];
    __shared__ float sb[128];
    int t = threadIdx.x;
    int base = blockIdx.x * 256;
    for (int i = t; i < 512; i += 256) ((float4*)sW)[i] = ((const float4*)W1)[i];
    if (t < 128) sb[t] = b1[t];
    #pragma unroll
    for (int i = 0; i < 4; i++) {
        int f = i * 1024 + t * 4;
        int row = f >> 4, k = f & 15;
        float4 v = make_float4(0.f, 0.f, 0.f, 0.f);
        if (base + row < N_NODES) v = *(const float4*)(x + (size_t)(base + row) * 16 + k);
        *(float4*)(sX + row * 17 + k) = v;
    }
    __syncthreads();
    int row = base + t;
    if (row >= N_NODES) return;
    float xr[16];
    #pragma unroll
    for (int k = 0; k < 16; k++) xr[k] = sX[t * 17 + k];
    #pragma unroll 4
    for (int cb = 0; cb < 16; cb++) {
        float acc[8];
        #pragma unroll
        for (int jj = 0; jj < 8; jj++) acc[jj] = sb[cb * 8 + jj];
        #pragma unroll
        for (int k = 0; k < 16; k++) {
            float xv = xr[k];
            #pragma unroll
            for (int jj = 0; jj < 8; jj++) acc[jj] = fmaf(xv, sW[k * 128 + cb * 8 + jj], acc[jj]);
        }
        half8 h;
        #pragma unroll
        for (int jj = 0; jj < 8; jj++) h[jj] = (_Float16)fmaxf(acc[jj], 0.f);
        *(half8*)(out + (size_t)row * 128 + cb * 8) = h;
    }
}

// ---------------- f16 MFMA GEMM: [N,128] @ [128,128], grid-stride tiles ----------------

#define GEMM_GRID 522

template <bool BIAS, bool RELU, bool DEC>
__global__ __launch_bounds__(256, 2) void gemm_mfma(const _Float16* __restrict__ A,
                                                    const _Float16* __restrict__ Wt,
                                                    const float* __restrict__ bias,
                                                    _Float16* __restrict__ C,
                                                    const float* __restrict__ W2,
                                                    const float* __restrict__ b2,
                                                    float* __restrict__ sm_out) {
    __shared__ _Float16 sA[64 * 128];
    __shared__ _Float16 sE[DEC ? 64 : 64 * 128];
    __shared__ float sW2[DEC ? 256 : 1];
    int t = threadIdx.x;
    int lane = t & 63;
    int w = t >> 6;
    int l15 = lane & 15;
    int l4 = lane >> 4;

    half8 bfrag[8][4];
    #pragma unroll
    for (int n = 0; n < 8; n++)
        #pragma unroll
        for (int kk = 0; kk < 4; kk++)
            bfrag[n][kk] = *(const half8*)(Wt + (n * 16 + l15) * 128 + kk * 32 + l4 * 8);

    float bcol[8];
    if constexpr (BIAS) {
        #pragma unroll
        for (int n = 0; n < 8; n++) bcol[n] = bias[n * 16 + l15];
    }
    float b20 = 0.f, b21 = 0.f;
    if constexpr (DEC) {
        if (t < 256) sW2[t] = W2[t];
        b20 = b2[0]; b21 = b2[1];
    }

    const int NT = (N_NODES + 63) / 64;
    for (int tile = blockIdx.x; tile < NT; tile += GEMM_GRID) {
        const _Float16* Ag = A + (size_t)tile * 64 * 128;
        #pragma unroll
        for (int i = 0; i < 4; i++) {
            int c = i * 256 + t;
            int row = c >> 4;
            int g = (c & 15) ^ (row & 7);
            const _Float16* src = Ag + row * 128 + g * 8;
            __builtin_amdgcn_global_load_lds(
                (const __attribute__((address_space(1))) void*)src,
                (__attribute__((address_space(3))) void*)(sA + (size_t)(i * 256 + w * 64) * 8),
                16, 0, 0);
        }
        __syncthreads();

        floatx4 acc[8];
        #pragma unroll
        for (int n = 0; n < 8; n++) acc[n] = (floatx4)(0.f);

        #pragma unroll
        for (int kk = 0; kk < 4; kk++) {
            int rloc = w * 16 + l15;
            int cl = kk * 4 + l4;
            int s = cl ^ (rloc & 7);
            half8 af = *(const half8*)(sA + rloc * 128 + s * 8);
            #pragma unroll
            for (int n = 0; n < 8; n++)
                acc[n] = __builtin_amdgcn_mfma_f32_16x16x32_f16(af, bfrag[n][kk], acc[n], 0, 0, 0);
        }

        size_t base_row = (size_t)tile * 64;
        if constexpr (DEC) {
            #pragma unroll
            for (int r = 0; r < 4; r++) {
                float p0 = 0.f, p1 = 0.f;
                #pragma unroll
                for (int n = 0; n < 8; n++) {
                    float v = acc[n][r];
                    if constexpr (BIAS) v += bcol[n];
                    if constexpr (RELU) v = fmaxf(v, 0.f);
                    int ch = n * 16 + l15;
                    p0 = fmaf(v, sW2[ch * 2 + 0], p0);
                    p1 = fmaf(v, sW2[ch * 2 + 1], p1);
                }
                #pragma unroll
                for (int m = 1; m < 16; m <<= 1) {
                    p0 += __shfl_xor(p0, m, 64);
                    p1 += __shfl_xor(p1, m, 64);
                }
                size_t grow = base_row + w * 16 + l4 * 4 + r;
                if (l15 == 0 && grow < N_NODES) {
                    float z0 = p0 + b20, z1 = p1 + b21;
                    float mx = fmaxf(z0, z1);
                    float e0 = expf(z0 - mx), e1 = expf(z1 - mx);
                    float si = 1.f / (e0 + e1);
                    *(float2*)(sm_out + grow * 2) = make_float2(e0 * si, e1 * si);
                }
            }
            __syncthreads();
        } else {
            #pragma unroll
            for (int n = 0; n < 8; n++) {
                #pragma unroll
                for (int r = 0; r < 4; r++) {
                    float v = acc[n][r];
                    if constexpr (BIAS) v += bcol[n];
                    if constexpr (RELU) v = fmaxf(v, 0.f);
                    int row = w * 16 + l4 * 4 + r;
                    sE[row * 128 + n * 16 + l15] = (_Float16)v;
                }
            }
            __syncthreads();
            #pragma unroll
            for (int i = 0; i < 4; i++) {
                int c = i * 256 + t;
                int row = c >> 4;
                if (base_row + row < N_NODES) {
                    *(float4*)((char*)C + (base_row + row) * 256 + (c & 15) * 16) =
                        *(const float4*)((const char*)sE + (size_t)c * 16);
                }
            }
        }
    }
}

// ---------------- GCN aggregation v2 ----------------
// Wave = 4 groups x 16 lanes. Group g owns edge e+g; lane q owns 8-channel
// chunk (half8, 16B gather). 8 edges in flight; cross-group shfl_xor reduce.

__device__ __forceinline__ float wdec(unsigned u) {
    unsigned short b = (unsigned short)(u >> 17);
    _Float16 h;
    __builtin_memcpy(&h, &b, 2);
    return (float)h;
}

__global__ __launch_bounds__(256) void agg_kernel(const _Float16* __restrict__ m,
                                                  const int* __restrict__ offs,
                                                  const unsigned long long* __restrict__ packed,
                                                  const unsigned* __restrict__ csr,
                                                  const float* __restrict__ dis,
                                                  const float* __restrict__ bias,
                                                  _Float16* __restrict__ out) {
    int wave = threadIdx.x >> 6;
    int lane = threadIdx.x & 63;
    int g = lane >> 4;      // edge slot within wave
    int q = lane & 15;      // 8-channel chunk
    int j = blockIdx.x * 4 + wave;
    if (j >= N_NODES) return;
    int s = offs[j];
    int num = (int)(packed[j] >> 40);

    float acc[8];
    if (g == 0) {
        float d = dis[j];
        float dd = d * d;
        half8 mv = *(const half8*)(m + (size_t)j * 128 + q * 8);
        #pragma unroll
        for (int i = 0; i < 8; i++) acc[i] = dd * (float)mv[i];
    } else {
        #pragma unroll
        for (int i = 0; i < 8; i++) acc[i] = 0.f;
    }

    int e = 0;
    for (; e + 8 <= num; e += 8) {
        unsigned u0 = csr[s + e + g];
        unsigned u1 = csr[s + e + 4 + g];
        half8 r0 = *(const half8*)(m + (size_t)(u0 & 0x1FFFF) * 128 + q * 8);
        half8 r1 = *(const half8*)(m + (size_t)(u1 & 0x1FFFF) * 128 + q * 8);
        float w0 = wdec(u0);
        float w1 = wdec(u1);
        #pragma unroll
        for (int i = 0; i < 8; i++) acc[i] = fmaf(w0, (float)r0[i], acc[i]);
        #pragma unroll
        for (int i = 0; i < 8; i++) acc[i] = fmaf(w1, (float)r1[i], acc[i]);
    }
    for (; e < num; e += 4) {
        if (e + g < num) {
            unsigned u0 = csr[s + e + g];
            half8 r0 = *(const half8*)(m + (size_t)(u0 & 0x1FFFF) * 128 + q * 8);
            float w0 = wdec(u0);
            #pragma unroll
            for (int i = 0; i < 8; i++) acc[i] = fmaf(w0, (float)r0[i], acc[i]);
        }
    }

    #pragma unroll
    for (int i = 0; i < 8; i++) {
        acc[i] += __shfl_xor(acc[i], 16, 64);
        acc[i] += __shfl_xor(acc[i], 32, 64);
    }

    if (g == 0) {
        float4 b0 = *(const float4*)(bias + q * 8);
        float4 b1 = *(const float4*)(bias + q * 8 + 4);
        float bb[8] = {b0.x, b0.y, b0.z, b0.w, b1.x, b1.y, b1.z, b1.w};
        half8 o;
        #pragma unroll
        for (int i = 0; i < 8; i++) o[i] = (_Float16)fmaxf(acc[i] + bb[i], 0.f);
        *(half8*)(out + (size_t)j * 128 + q * 8) = o;
    }
}

// ---------------- launch ----------------

extern "C" void kernel_launch(void* const* d_in, const int* in_sizes, int n_in,
                              void* d_out, int out_size, void* d_ws, size_t ws_size,
                              hipStream_t stream) {
    const float* x      = (const float*)d_in[0];
    const int*   ei     = (const int*)d_in[1];
    const float* ew     = (const float*)d_in[2];
    const float* enc_W1 = (const float*)d_in[3];
    const float* enc_b1 = (const float*)d_in[4];
    const float* enc_W2 = (const float*)d_in[5];
    const float* enc_b2 = (const float*)d_in[6];
    const float* c1_W   = (const float*)d_in[7];
    const float* c1_b   = (const float*)d_in[8];
    const float* c2_W   = (const float*)d_in[9];
    const float* c2_b   = (const float*)d_in[10];
    const float* dec_W1 = (const float*)d_in[11];
    const float* dec_b1 = (const float*)d_in[12];
    const float* dec_W2 = (const float*)d_in[13];
    const float* dec_b2 = (const float*)d_in[14];
    float* out = (float*)d_out;

    char* ws = (char*)d_ws;
    _Float16* B1 = (_Float16*)(ws);                          // 25,600,000
    _Float16* B2 = (_Float16*)(ws + 25600000);               // 25,600,000
    _Float16* Wt = (_Float16*)(ws + 51200000);               // 131,072
    unsigned long long* packed = (unsigned long long*)(ws + 51331072);  // 800,000
    int*   gcur    = (int*)  (ws + 52131072);                // 256
    float* dis     = (float*)(ws + 52131328);                // 400,000
    int*   offs    = (int*)  (ws + 52531328);                // 400,000
    unsigned short* tickets = (unsigned short*)(ws + 52931328); // 3,200,000
    unsigned* csr  = (unsigned*)(ws + 56131328);             // 6,400,000
    // end ~62.5 MB

    // zero packed + gcur (contiguous)
    hipMemsetAsync(packed, 0, 800256, stream);

    edge_pass1<<<(N_EDGES + 255) / 256, 256, 0, stream>>>(ei, ew, packed, tickets);
    node_pass<<<(N_NODES + 255) / 256, 256, 0, stream>>>(packed, dis, offs, gcur);
    edge_pass2<<<(N_EDGES + 255) / 256, 256, 0, stream>>>(ei, ew, dis, offs, tickets, csr);

    prep_w<<<64, 256, 0, stream>>>(enc_W2, c1_W, c2_W, dec_W1, Wt);
    enc1_kernel<<<(N_NODES + 255) / 256, 256, 0, stream>>>(x, enc_W1, enc_b1, B1);

    gemm_mfma<true, false, false><<<GEMM_GRID, 256, 0, stream>>>(B1, Wt + 0 * 16384, enc_b2, B2, nullptr, nullptr, nullptr);
    gemm_mfma<false, false, false><<<GEMM_GRID, 256, 0, stream>>>(B2, Wt + 1 * 16384, nullptr, B1, nullptr, nullptr, nullptr);
    agg_kernel<<<N_NODES / 4, 256, 0, stream>>>(B1, offs, packed, csr, dis, c1_b, B2);
    gemm_mfma<false, false, false><<<GEMM_GRID, 256, 0, stream>>>(B2, Wt + 2 * 16384, nullptr, B1, nullptr, nullptr, nullptr);
    agg_kernel<<<N_NODES / 4, 256, 0, stream>>>(B1, offs, packed, csr, dis, c2_b, B2);
    gemm_mfma<true, true, true><<<GEMM_GRID, 256, 0, stream>>>(B2, Wt + 3 * 16384, dec_b1, nullptr, dec_W2, dec_b2, out);
}